// Round 1
// baseline (53.394 us; speedup 1.0000x reference)
//
#include <hip/hip_runtime.h>

// Always_ op == sliding-window min over the time axis:
//   out[b,j] = min_{i=j..j+hi} padded(signal)[b,i],  pad = last value.
// lo=0, hi=256 -> window 257 = CHUNK+1, so each window spans exactly the
// suffix of chunk k and the prefix of chunk k+1 (CHUNK=256).

#define CHUNK 256

__global__ __launch_bounds__(CHUNK) void sliding_min_kernel(
    const float* __restrict__ sig, float* __restrict__ out, int T) {
    __shared__ float sA[CHUNK];
    __shared__ float sB[CHUNK];

    const int t = threadIdx.x;      // position within chunk
    const int k = blockIdx.x;       // chunk index
    const int b = blockIdx.y;       // batch index
    const int base = k * CHUNK;
    const float* s = sig + (size_t)b * T;

    // Load chunk k and chunk k+1 (clamped to T-1: 'last' padding semantics).
    sA[t] = s[base + t];
    const int idxB = base + CHUNK + t;
    sB[t] = s[idxB < T ? idxB : (T - 1)];
    __syncthreads();

    // Simultaneous doubling scans:
    //   sA -> inclusive suffix-min, sB -> inclusive prefix-min.
    #pragma unroll
    for (int off = 1; off < CHUNK; off <<= 1) {
        const float va = sA[t];
        const float wa = (t + off < CHUNK) ? sA[t + off] : va;
        const float vb = sB[t];
        const float wb = (t >= off) ? sB[t - off] : vb;
        __syncthreads();
        sA[t] = fminf(va, wa);
        sB[t] = fminf(vb, wb);
        __syncthreads();
    }

    // out[b, base+t] = min over [base+t, base+t+256]
    out[(size_t)b * T + base + t] = fminf(sA[t], sB[t]);
}

extern "C" void kernel_launch(void* const* d_in, const int* in_sizes, int n_in,
                              void* d_out, int out_size, void* d_ws, size_t ws_size,
                              hipStream_t stream) {
    const float* sig = (const float*)d_in[0];
    float* out = (float*)d_out;

    const int B = 4;
    const int T = in_sizes[0] / B;      // 8192
    dim3 grid(T / CHUNK, B);            // 32 x 4 = 128 workgroups
    sliding_min_kernel<<<grid, CHUNK, 0, stream>>>(sig, out, T);
}

// Round 2
// 52.056 us; speedup vs baseline: 1.0257x; 1.0257x over previous
//
#include <hip/hip_runtime.h>

// Always_ op == sliding-window min over time:
//   out[b,j] = min_{i=j..j+256} padded(signal)[b,i],  pad = last value.
// Window 257 = CHUNK+1: window at j=base+t spans suffix of chunk k (256-t
// elems) + prefix of chunk k+1 (t+1 elems). Wave-shuffle scans, 1 barrier.

#define CHUNK 256

__global__ __launch_bounds__(CHUNK) void sliding_min_kernel(
    const float* __restrict__ sig, float* __restrict__ out, int T) {
    const int t    = threadIdx.x;       // position within chunk (0..255)
    const int lane = t & 63;
    const int w    = t >> 6;            // wave id 0..3
    const int base = blockIdx.x * CHUNK;
    const float* s = sig + (size_t)blockIdx.y * T;

    // a: chunk k element; b: chunk k+1 element (clamped -> 'last' padding)
    const float a = s[base + t];
    const int idxB = base + CHUNK + t;
    const float bv = s[idxB < T ? idxB : (T - 1)];

    // Wave-level inclusive suffix-min of a (6 shuffle steps, no barriers).
    float sa = a;
    #pragma unroll
    for (int off = 1; off < 64; off <<= 1) {
        const float o = __shfl_down(sa, off, 64);
        if (lane + off < 64) sa = fminf(sa, o);
    }
    // Wave-level inclusive prefix-min of b.
    float pb = bv;
    #pragma unroll
    for (int off = 1; off < 64; off <<= 1) {
        const float o = __shfl_up(pb, off, 64);
        if (lane >= off) pb = fminf(pb, o);
    }

    // Cross-wave combine: wave w needs min of A-waves > w and B-waves < w.
    __shared__ float wMinA[4];          // full min of wave's A = suffix at lane 0
    __shared__ float wMinB[4];          // full min of wave's B = prefix at lane 63
    if (lane == 0)  wMinA[w] = sa;
    if (lane == 63) wMinB[w] = pb;
    __syncthreads();

    float r = fminf(sa, pb);
    #pragma unroll
    for (int ww = 0; ww < 4; ++ww) {    // wave-uniform conditions: no divergence cost
        if (ww > w) r = fminf(r, wMinA[ww]);
        if (ww < w) r = fminf(r, wMinB[ww]);
    }

    out[(size_t)blockIdx.y * T + base + t] = r;
}

extern "C" void kernel_launch(void* const* d_in, const int* in_sizes, int n_in,
                              void* d_out, int out_size, void* d_ws, size_t ws_size,
                              hipStream_t stream) {
    const float* sig = (const float*)d_in[0];
    float* out = (float*)d_out;

    const int B = 4;
    const int T = in_sizes[0] / B;      // 8192
    dim3 grid(T / CHUNK, B);            // 32 x 4 = 128 workgroups
    sliding_min_kernel<<<grid, CHUNK, 0, stream>>>(sig, out, T);
}